// Round 10
// baseline (146.575 us; speedup 1.0000x reference)
//
#include <hip/hip_runtime.h>
#include <math.h>

#define Bv  4
#define Cv  64
#define DCv 32
#define Fv  128
#define Tv  512
#define FT  (Fv * 512)

// ---------------------------------------------------------------------------
// K1: PURE conv1 + BN + PReLU -> Q. grid (b,f,half)=1024 x 256, 2-deep
// software pipeline of 8-channel batches. Proven: ~52 VGPR -> no spill.
// ---------------------------------------------------------------------------
#define LOADX(arr, kb) { _Pragma("unroll") \
    for (int i = 0; i < 8; ++i) arr[i] = px[(size_t)((kb) * 8 + i) * FT]; }
#define CONVB(arr, kb) { _Pragma("unroll") \
    for (int c = 0; c < DCv; ++c) { \
        const float* wr = w1 + c * Cv + (kb) * 8; \
        float a = acc[c]; \
        _Pragma("unroll") for (int i = 0; i < 8; ++i) a = fmaf(wr[i], arr[i], a); \
        acc[c] = a; } }

__global__ __launch_bounds__(256, 4)
void k1_conv(const float* __restrict__ inp,
             const float* __restrict__ w1, const float* __restrict__ b1,
             const float* __restrict__ g1, const float* __restrict__ be1,
             const float* __restrict__ m1, const float* __restrict__ v1,
             const float* __restrict__ a1,
             float* __restrict__ Qws)
{
    __shared__ float sS1[DCv], sT1[DCv];

    const int tid  = threadIdx.x;
    const int bid  = blockIdx.x;
    const int half = bid & 1;
    const int bf   = bid >> 1;
    const int b    = bf >> 7;
    const int f    = bf & 127;

    if (tid < DCv) {
        float s = g1[tid] / sqrtf(v1[tid] + 1e-5f);
        sS1[tid] = s;
        sT1[tid] = (b1[tid] - m1[tid]) * s + be1[tid];
    }
    const float alpha1 = a1[0];
    __syncthreads();

    const int t = half * 256 + tid;
    const float* px = inp + ((size_t)(b * Cv) * Fv + f) * Tv + t;

    float acc[DCv];
    #pragma unroll
    for (int c = 0; c < DCv; ++c) acc[c] = 0.f;

    float xa[8], xb[8];
    LOADX(xa, 0);
    LOADX(xb, 1); CONVB(xa, 0);
    LOADX(xa, 2); CONVB(xb, 1);
    LOADX(xb, 3); CONVB(xa, 2);
    LOADX(xa, 4); CONVB(xb, 3);
    LOADX(xb, 5); CONVB(xa, 4);
    LOADX(xa, 6); CONVB(xb, 5);
    LOADX(xb, 7); CONVB(xa, 6);
    CONVB(xb, 7);

    float* qg = Qws + ((size_t)bf * Tv + t) * DCv;
    #pragma unroll
    for (int j = 0; j < 8; ++j) {
        float z0 = fmaf(acc[4*j+0], sS1[4*j+0], sT1[4*j+0]);
        float z1 = fmaf(acc[4*j+1], sS1[4*j+1], sT1[4*j+1]);
        float z2 = fmaf(acc[4*j+2], sS1[4*j+2], sT1[4*j+2]);
        float z3 = fmaf(acc[4*j+3], sS1[4*j+3], sT1[4*j+3]);
        float4 v;
        v.x = z0 >= 0.f ? z0 : alpha1 * z0;
        v.y = z1 >= 0.f ? z1 : alpha1 * z1;
        v.z = z2 >= 0.f ? z2 : alpha1 * z2;
        v.w = z3 >= 0.f ? z3 : alpha1 * z3;
        *(float4*)&qg[j * 4] = v;
    }
}

// ---------------------------------------------------------------------------
// KM: M = Q Q^T / sqrt(32), one block per bf. 256 threads = 4 k-slice groups
// x 64 lanes; partials combined through 16 KB LDS. No atomics, 1 barrier.
// ---------------------------------------------------------------------------
__global__ __launch_bounds__(256)
void km_build(const float* __restrict__ Qws, float* __restrict__ Mfull)
{
    __shared__ __align__(16) float sP[4][1024];  // 16 KB

    const int tid   = threadIdx.x;
    const int bf    = blockIdx.x;
    const int slice = tid >> 6;
    const int l     = tid & 63;
    const int c1b   = l >> 3;
    const int c2b   = l & 7;

    const float* qp = Qws + ((size_t)bf * Tv + slice * 128) * DCv;
    float4 r0 = {0,0,0,0}, r1 = {0,0,0,0}, r2 = {0,0,0,0}, r3 = {0,0,0,0};
    #pragma unroll 4
    for (int i = 0; i < 128; ++i) {
        const float4 qa = *(const float4*)&qp[i * 32 + c1b * 4];
        const float4 qb = *(const float4*)&qp[i * 32 + c2b * 4];
        r0.x = fmaf(qa.x, qb.x, r0.x); r0.y = fmaf(qa.x, qb.y, r0.y);
        r0.z = fmaf(qa.x, qb.z, r0.z); r0.w = fmaf(qa.x, qb.w, r0.w);
        r1.x = fmaf(qa.y, qb.x, r1.x); r1.y = fmaf(qa.y, qb.y, r1.y);
        r1.z = fmaf(qa.y, qb.z, r1.z); r1.w = fmaf(qa.y, qb.w, r1.w);
        r2.x = fmaf(qa.z, qb.x, r2.x); r2.y = fmaf(qa.z, qb.y, r2.y);
        r2.z = fmaf(qa.z, qb.z, r2.z); r2.w = fmaf(qa.z, qb.w, r2.w);
        r3.x = fmaf(qa.w, qb.x, r3.x); r3.y = fmaf(qa.w, qb.y, r3.y);
        r3.z = fmaf(qa.w, qb.z, r3.z); r3.w = fmaf(qa.w, qb.w, r3.w);
    }
    *(float4*)&sP[slice][(c1b * 4 + 0) * DCv + c2b * 4] = r0;
    *(float4*)&sP[slice][(c1b * 4 + 1) * DCv + c2b * 4] = r1;
    *(float4*)&sP[slice][(c1b * 4 + 2) * DCv + c2b * 4] = r2;
    *(float4*)&sP[slice][(c1b * 4 + 3) * DCv + c2b * 4] = r3;
    __syncthreads();

    const float INV = 0.17677669529663687f;  // 1/sqrt(32)
    float4 v0 = *(const float4*)&sP[0][tid * 4];
    float4 v1 = *(const float4*)&sP[1][tid * 4];
    float4 v2 = *(const float4*)&sP[2][tid * 4];
    float4 v3 = *(const float4*)&sP[3][tid * 4];
    float4 o;
    o.x = ((v0.x + v1.x) + (v2.x + v3.x)) * INV;
    o.y = ((v0.y + v1.y) + (v2.y + v3.y)) * INV;
    o.z = ((v0.z + v1.z) + (v2.z + v3.z)) * INV;
    o.w = ((v0.w + v1.w) + (v2.w + v3.w)) * INV;
    *(float4*)&Mfull[(size_t)bf * 1024 + tid * 4] = o;
}

// ---------------------------------------------------------------------------
// KS: O = Mfull*q computed IN PLACE over Qws (O[:,t] depends only on q[:,t]),
// plus per-(bf,128-t-chunk) softmax stats through a 16.5 KB transpose tile.
// grid (bf x 4 chunks) = 2048 blocks x 128 thr -> occupancy-rich. Live set
// q[32] + 8 accs ~ 48 regs: fits the 64-VGPR attractor.
// ---------------------------------------------------------------------------
__global__ __launch_bounds__(128)
void ks_o_stats(float* __restrict__ Qio, const float* __restrict__ Mfull,
                float* __restrict__ Smx, float* __restrict__ Ssum)
{
    __shared__ float sT[DCv][132];   // 16.5 KB (pad 4: lane-contig reads stay clean)

    const int tid   = threadIdx.x;
    const int bid   = blockIdx.x;
    const int bf    = bid >> 2;
    const int chunk = bid & 3;
    const int f     = bf & 127;
    const int t     = chunk * 128 + tid;

    float q[DCv];
    float* qg = Qio + ((size_t)bf * Tv + t) * DCv;
    #pragma unroll
    for (int j = 0; j < 8; ++j) {
        float4 v = *(const float4*)&qg[j * 4];
        q[4*j] = v.x; q[4*j+1] = v.y; q[4*j+2] = v.z; q[4*j+3] = v.w;
    }

    const int limit = f + (Tv - Fv + 1);   // valid iff t < limit (>= 385 always)
    const bool valid = t < limit;

    const float* Mg = Mfull + (size_t)bf * 1024;   // block-uniform -> scalar loads
    #pragma unroll
    for (int j = 0; j < 8; ++j) {
        float o0, o1, o2, o3;
        {
            const float* mr = Mg + (4*j+0) * DCv;
            float a0 = 0.f, a1 = 0.f;
            #pragma unroll
            for (int k = 0; k < 16; ++k) { a0 = fmaf(mr[k], q[k], a0); a1 = fmaf(mr[k+16], q[k+16], a1); }
            o0 = a0 + a1;
        }
        {
            const float* mr = Mg + (4*j+1) * DCv;
            float a0 = 0.f, a1 = 0.f;
            #pragma unroll
            for (int k = 0; k < 16; ++k) { a0 = fmaf(mr[k], q[k], a0); a1 = fmaf(mr[k+16], q[k+16], a1); }
            o1 = a0 + a1;
        }
        {
            const float* mr = Mg + (4*j+2) * DCv;
            float a0 = 0.f, a1 = 0.f;
            #pragma unroll
            for (int k = 0; k < 16; ++k) { a0 = fmaf(mr[k], q[k], a0); a1 = fmaf(mr[k+16], q[k+16], a1); }
            o2 = a0 + a1;
        }
        {
            const float* mr = Mg + (4*j+3) * DCv;
            float a0 = 0.f, a1 = 0.f;
            #pragma unroll
            for (int k = 0; k < 16; ++k) { a0 = fmaf(mr[k], q[k], a0); a1 = fmaf(mr[k+16], q[k+16], a1); }
            o3 = a0 + a1;
        }
        sT[4*j+0][tid] = valid ? o0 : -INFINITY;
        sT[4*j+1][tid] = valid ? o1 : -INFINITY;
        sT[4*j+2][tid] = valid ? o2 : -INFINITY;
        sT[4*j+3][tid] = valid ? o3 : -INFINITY;
        float4 v; v.x = o0; v.y = o1; v.z = o2; v.w = o3;
        *(float4*)&qg[j * 4] = v;    // O overwrites q (finite values, unmasked)
    }
    __syncthreads();

    // 2 waves x 16 rows each; each row always contains >=1 valid t (limit>=385)
    const int w = tid >> 6, l = tid & 63;
    #pragma unroll
    for (int r = 0; r < 16; ++r) {
        const int c = w * 16 + r;
        float v0 = sT[c][l], v1 = sT[c][64 + l];
        float mx = fmaxf(v0, v1);
        #pragma unroll
        for (int s = 1; s < 64; s <<= 1) mx = fmaxf(mx, __shfl_xor(mx, s));
        float sum = __expf(v0 - mx) + __expf(v1 - mx);
        #pragma unroll
        for (int s = 1; s < 64; s <<= 1) sum += __shfl_xor(sum, s);
        if (l == 0) {
            Smx [(size_t)bf * 128 + c * 4 + chunk] = mx;
            Ssum[(size_t)bf * 128 + c * 4 + chunk] = sum;
        }
    }
}

// ---------------------------------------------------------------------------
// K2: pure output stream. Combine 4 chunk-stats (tiny), read O (contiguous,
// in-place over Qws), normalize -> P, conv2 + BN + PReLU + residual -> out.
// grid 1024 x 256, tiny LDS -> 4 blocks/CU (wave cap). Live set P[32]+rin[32]
// = the r7-proven 64-VGPR no-spill shape. ONE barrier.
// ---------------------------------------------------------------------------
__global__ __launch_bounds__(256, 4)
void k2_out(const float* __restrict__ inp,
            const float* __restrict__ Ows,
            const float* __restrict__ Smx, const float* __restrict__ Ssum,
            const float* __restrict__ wp, const float* __restrict__ bp,
            const float* __restrict__ g2, const float* __restrict__ be2,
            const float* __restrict__ m2, const float* __restrict__ v2,
            const float* __restrict__ a2,
            float* __restrict__ out)
{
    __shared__ float sMx[DCv], sRZ[DCv];
    __shared__ float sS2[Cv], sT2[Cv];

    const int tid = threadIdx.x;
    const int bid = blockIdx.x;
    const int bf  = bid >> 1;
    const int b   = bf >> 7;
    const int f   = bf & 127;
    const int t   = (bid & 1) * 256 + tid;

    if (tid < DCv) {
        const float* pm = Smx  + (size_t)bf * 128 + tid * 4;
        const float* ps = Ssum + (size_t)bf * 128 + tid * 4;
        float m0 = pm[0], m1 = pm[1], m2_ = pm[2], m3 = pm[3];
        float mx = fmaxf(fmaxf(m0, m1), fmaxf(m2_, m3));
        float Z = ps[0] * __expf(m0 - mx) + ps[1] * __expf(m1 - mx)
                + ps[2] * __expf(m2_ - mx) + ps[3] * __expf(m3 - mx);
        sMx[tid] = mx;
        sRZ[tid] = 1.f / Z;
    } else if (tid >= 32 && tid < 32 + Cv) {
        const int o = tid - 32;
        float s = g2[o] / sqrtf(v2[o] + 1e-5f);
        sS2[o] = s;
        sT2[o] = (bp[o] - m2[o]) * s + be2[o];
    }
    const float alpha2 = a2[0];
    __syncthreads();

    // O column (contiguous 128 B/thread)
    float P[DCv];
    const float* og = Ows + ((size_t)bf * Tv + t) * DCv;
    #pragma unroll
    for (int j = 0; j < 8; ++j) {
        float4 v = *(const float4*)&og[j * 4];
        P[4*j] = v.x; P[4*j+1] = v.y; P[4*j+2] = v.z; P[4*j+3] = v.w;
    }

    const int limit = f + (Tv - Fv + 1);
    const bool valid = t < limit;
    #pragma unroll
    for (int c = 0; c < DCv; ++c)
        P[c] = valid ? __expf(P[c] - sMx[c]) * sRZ[c] : 0.f;

    // conv2 + BN + PReLU + residual; rin prefetched per half
    const float* pin = inp + ((size_t)(b * Cv) * Fv + f) * Tv + t;
    float* pot       = out + ((size_t)(b * Cv) * Fv + f) * Tv + t;

    float rin0[32];
    #pragma unroll
    for (int i = 0; i < 32; ++i) rin0[i] = pin[(size_t)i * FT];

    #pragma unroll 4
    for (int oo = 0; oo < 32; ++oo) {
        const float* wr = wp + oo * DCv;  // uniform -> scalar loads
        float a0 = 0.f, a1 = 0.f, a2_ = 0.f, a3 = 0.f;
        #pragma unroll
        for (int k = 0; k < 8; ++k) {
            a0  = fmaf(wr[k],      P[k],      a0);
            a1  = fmaf(wr[k + 8],  P[k + 8],  a1);
            a2_ = fmaf(wr[k + 16], P[k + 16], a2_);
            a3  = fmaf(wr[k + 24], P[k + 24], a3);
        }
        float z = fmaf((a0 + a1) + (a2_ + a3), sS2[oo], sT2[oo]);
        z = z >= 0.f ? z : alpha2 * z;
        pot[(size_t)oo * FT] = z + rin0[oo];
    }

    float rin1[32];
    #pragma unroll
    for (int i = 0; i < 32; ++i) rin1[i] = pin[(size_t)(i + 32) * FT];

    #pragma unroll 4
    for (int oo = 0; oo < 32; ++oo) {
        const int o = 32 + oo;
        const float* wr = wp + o * DCv;
        float a0 = 0.f, a1 = 0.f, a2_ = 0.f, a3 = 0.f;
        #pragma unroll
        for (int k = 0; k < 8; ++k) {
            a0  = fmaf(wr[k],      P[k],      a0);
            a1  = fmaf(wr[k + 8],  P[k + 8],  a1);
            a2_ = fmaf(wr[k + 16], P[k + 16], a2_);
            a3  = fmaf(wr[k + 24], P[k + 24], a3);
        }
        float z = fmaf((a0 + a1) + (a2_ + a3), sS2[o], sT2[o]);
        z = z >= 0.f ? z : alpha2 * z;
        pot[(size_t)o * FT] = z + rin1[oo];
    }
}

extern "C" void kernel_launch(void* const* d_in, const int* in_sizes, int n_in,
                              void* d_out, int out_size, void* d_ws, size_t ws_size,
                              hipStream_t stream) {
    const float* inp = (const float*)d_in[0];
    const float* w1  = (const float*)d_in[1];
    const float* b1  = (const float*)d_in[2];
    const float* g1  = (const float*)d_in[3];
    const float* be1 = (const float*)d_in[4];
    const float* m1  = (const float*)d_in[5];
    const float* v1  = (const float*)d_in[6];
    const float* a1  = (const float*)d_in[7];
    const float* wp  = (const float*)d_in[8];
    const float* bp  = (const float*)d_in[9];
    const float* g2  = (const float*)d_in[10];
    const float* be2 = (const float*)d_in[11];
    const float* m2  = (const float*)d_in[12];
    const float* v2  = (const float*)d_in[13];
    const float* a2  = (const float*)d_in[14];

    float* Qws   = (float*)d_ws;                            // 8,388,608 f = 33.6 MB (Q, then O in place)
    float* Mfull = Qws   + (size_t)Bv * Fv * Tv * DCv;      //   524,288 f =  2.1 MB
    float* Smx   = Mfull + (size_t)512 * 1024;              //    65,536 f
    float* Ssum  = Smx   + (size_t)512 * 128;               //    65,536 f

    k1_conv<<<dim3(Bv * Fv * 2), dim3(256), 0, stream>>>(
        inp, w1, b1, g1, be1, m1, v1, a1, Qws);
    km_build<<<dim3(Bv * Fv), dim3(256), 0, stream>>>(Qws, Mfull);
    ks_o_stats<<<dim3(Bv * Fv * 4), dim3(128), 0, stream>>>(Qws, Mfull, Smx, Ssum);
    k2_out<<<dim3(Bv * Fv * 2), dim3(256), 0, stream>>>(
        inp, Qws, Smx, Ssum, wp, bp, g2, be2, m2, v2, a2, (float*)d_out);
}

// Round 11
// 111.452 us; speedup vs baseline: 1.3151x; 1.3151x over previous
//
#include <hip/hip_runtime.h>
#include <math.h>

#define Bv  4
#define Cv  64
#define DCv 32
#define Fv  128
#define Tv  512
#define FT  (Fv * 512)

// ---------------------------------------------------------------------------
// K1: PURE conv1 + BN + PReLU -> Q. grid (b,f,half)=1024 x 256, 2-deep
// software pipeline of 8-channel batches. Proven: ~52 VGPR -> no spill.
// ---------------------------------------------------------------------------
#define LOADX(arr, kb) { _Pragma("unroll") \
    for (int i = 0; i < 8; ++i) arr[i] = px[(size_t)((kb) * 8 + i) * FT]; }
#define CONVB(arr, kb) { _Pragma("unroll") \
    for (int c = 0; c < DCv; ++c) { \
        const float* wr = w1 + c * Cv + (kb) * 8; \
        float a = acc[c]; \
        _Pragma("unroll") for (int i = 0; i < 8; ++i) a = fmaf(wr[i], arr[i], a); \
        acc[c] = a; } }

__global__ __launch_bounds__(256, 4)
void k1_conv(const float* __restrict__ inp,
             const float* __restrict__ w1, const float* __restrict__ b1,
             const float* __restrict__ g1, const float* __restrict__ be1,
             const float* __restrict__ m1, const float* __restrict__ v1,
             const float* __restrict__ a1,
             float* __restrict__ Qws)
{
    __shared__ float sS1[DCv], sT1[DCv];

    const int tid  = threadIdx.x;
    const int bid  = blockIdx.x;
    const int half = bid & 1;
    const int bf   = bid >> 1;
    const int b    = bf >> 7;
    const int f    = bf & 127;

    if (tid < DCv) {
        float s = g1[tid] / sqrtf(v1[tid] + 1e-5f);
        sS1[tid] = s;
        sT1[tid] = (b1[tid] - m1[tid]) * s + be1[tid];
    }
    const float alpha1 = a1[0];
    __syncthreads();

    const int t = half * 256 + tid;
    const float* px = inp + ((size_t)(b * Cv) * Fv + f) * Tv + t;

    float acc[DCv];
    #pragma unroll
    for (int c = 0; c < DCv; ++c) acc[c] = 0.f;

    float xa[8], xb[8];
    LOADX(xa, 0);
    LOADX(xb, 1); CONVB(xa, 0);
    LOADX(xa, 2); CONVB(xb, 1);
    LOADX(xb, 3); CONVB(xa, 2);
    LOADX(xa, 4); CONVB(xb, 3);
    LOADX(xb, 5); CONVB(xa, 4);
    LOADX(xa, 6); CONVB(xb, 5);
    LOADX(xb, 7); CONVB(xa, 6);
    CONVB(xb, 7);

    float* qg = Qws + ((size_t)bf * Tv + t) * DCv;
    #pragma unroll
    for (int j = 0; j < 8; ++j) {
        float z0 = fmaf(acc[4*j+0], sS1[4*j+0], sT1[4*j+0]);
        float z1 = fmaf(acc[4*j+1], sS1[4*j+1], sT1[4*j+1]);
        float z2 = fmaf(acc[4*j+2], sS1[4*j+2], sT1[4*j+2]);
        float z3 = fmaf(acc[4*j+3], sS1[4*j+3], sT1[4*j+3]);
        float4 v;
        v.x = z0 >= 0.f ? z0 : alpha1 * z0;
        v.y = z1 >= 0.f ? z1 : alpha1 * z1;
        v.z = z2 >= 0.f ? z2 : alpha1 * z2;
        v.w = z3 >= 0.f ? z3 : alpha1 * z3;
        *(float4*)&qg[j * 4] = v;
    }
}

// ---------------------------------------------------------------------------
// KM: M = Q Q^T / sqrt(32) (symmetric -> [c][k] == [k][c]). One block per bf.
// Proven GEMM-tiled pattern, ~68% VALU peak. No atomics, 1 barrier.
// ---------------------------------------------------------------------------
__global__ __launch_bounds__(256)
void km_build(const float* __restrict__ Qws, float* __restrict__ Mfull)
{
    __shared__ __align__(16) float sP[4][1024];  // 16 KB

    const int tid   = threadIdx.x;
    const int bf    = blockIdx.x;
    const int slice = tid >> 6;
    const int l     = tid & 63;
    const int c1b   = l >> 3;
    const int c2b   = l & 7;

    const float* qp = Qws + ((size_t)bf * Tv + slice * 128) * DCv;
    float4 r0 = {0,0,0,0}, r1 = {0,0,0,0}, r2 = {0,0,0,0}, r3 = {0,0,0,0};
    #pragma unroll 4
    for (int i = 0; i < 128; ++i) {
        const float4 qa = *(const float4*)&qp[i * 32 + c1b * 4];
        const float4 qb = *(const float4*)&qp[i * 32 + c2b * 4];
        r0.x = fmaf(qa.x, qb.x, r0.x); r0.y = fmaf(qa.x, qb.y, r0.y);
        r0.z = fmaf(qa.x, qb.z, r0.z); r0.w = fmaf(qa.x, qb.w, r0.w);
        r1.x = fmaf(qa.y, qb.x, r1.x); r1.y = fmaf(qa.y, qb.y, r1.y);
        r1.z = fmaf(qa.y, qb.z, r1.z); r1.w = fmaf(qa.y, qb.w, r1.w);
        r2.x = fmaf(qa.z, qb.x, r2.x); r2.y = fmaf(qa.z, qb.y, r2.y);
        r2.z = fmaf(qa.z, qb.z, r2.z); r2.w = fmaf(qa.z, qb.w, r2.w);
        r3.x = fmaf(qa.w, qb.x, r3.x); r3.y = fmaf(qa.w, qb.y, r3.y);
        r3.z = fmaf(qa.w, qb.z, r3.z); r3.w = fmaf(qa.w, qb.w, r3.w);
    }
    *(float4*)&sP[slice][(c1b * 4 + 0) * DCv + c2b * 4] = r0;
    *(float4*)&sP[slice][(c1b * 4 + 1) * DCv + c2b * 4] = r1;
    *(float4*)&sP[slice][(c1b * 4 + 2) * DCv + c2b * 4] = r2;
    *(float4*)&sP[slice][(c1b * 4 + 3) * DCv + c2b * 4] = r3;
    __syncthreads();

    const float INV = 0.17677669529663687f;  // 1/sqrt(32)
    float4 v0 = *(const float4*)&sP[0][tid * 4];
    float4 v1 = *(const float4*)&sP[1][tid * 4];
    float4 v2 = *(const float4*)&sP[2][tid * 4];
    float4 v3 = *(const float4*)&sP[3][tid * 4];
    float4 o;
    o.x = ((v0.x + v1.x) + (v2.x + v3.x)) * INV;
    o.y = ((v0.y + v1.y) + (v2.y + v3.y)) * INV;
    o.z = ((v0.z + v1.z) + (v2.z + v3.z)) * INV;
    o.w = ((v0.w + v1.w) + (v2.w + v3.w)) * INV;
    *(float4*)&Mfull[(size_t)bf * 1024 + tid * 4] = o;
}

// ---------------------------------------------------------------------------
// KPREP: fold BN2 scale into W2 (W2f[oc][k] = wp*s2[oc]) and bias (B2f[oc]).
// One block, ~2 us.
// ---------------------------------------------------------------------------
__global__ __launch_bounds__(512)
void kprep(const float* __restrict__ wp, const float* __restrict__ bp,
           const float* __restrict__ g2, const float* __restrict__ be2,
           const float* __restrict__ m2, const float* __restrict__ v2,
           float* __restrict__ W2f, float* __restrict__ B2f)
{
    const int tid = threadIdx.x;          // 512 threads x 1 float4 = 2048 elems
    const int oc  = tid >> 3;
    const float s = g2[oc] * rsqrtf(v2[oc] + 1e-5f);
    float4 v = *(const float4*)&wp[tid * 4];
    v.x *= s; v.y *= s; v.z *= s; v.w *= s;
    *(float4*)&W2f[tid * 4] = v;
    if (tid < Cv) B2f[tid] = (bp[tid] - m2[tid]) * (g2[tid] * rsqrtf(v2[tid] + 1e-5f)) + be2[tid];
}

// ---------------------------------------------------------------------------
// KF: fused O = M*Q -> mask -> softmax -> P -> OUT = W2f*P + B2f -> PReLU ->
// + residual. Per bf, 512 thr (8 waves), ~80 KB LDS -> 2 blocks/CU.
// GEMM-tiled like km: lane owns a 4c x 4t register tile; operands via
// float4 LDS reads (A rows padded to 36 to spread banks); 64 FMA per 8 LDS
// reads. Live set ~55 regs -> fits the 64-VGPR attractor by construction.
// ---------------------------------------------------------------------------
#define GEMM_CC(ACC, cc, a)                                       \
    ACC[(cc)*4+0] = fmaf(a.x, x0.x, ACC[(cc)*4+0]);               \
    ACC[(cc)*4+0] = fmaf(a.y, x1.x, ACC[(cc)*4+0]);               \
    ACC[(cc)*4+0] = fmaf(a.z, x2.x, ACC[(cc)*4+0]);               \
    ACC[(cc)*4+0] = fmaf(a.w, x3.x, ACC[(cc)*4+0]);               \
    ACC[(cc)*4+1] = fmaf(a.x, x0.y, ACC[(cc)*4+1]);               \
    ACC[(cc)*4+1] = fmaf(a.y, x1.y, ACC[(cc)*4+1]);               \
    ACC[(cc)*4+1] = fmaf(a.z, x2.y, ACC[(cc)*4+1]);               \
    ACC[(cc)*4+1] = fmaf(a.w, x3.y, ACC[(cc)*4+1]);               \
    ACC[(cc)*4+2] = fmaf(a.x, x0.z, ACC[(cc)*4+2]);               \
    ACC[(cc)*4+2] = fmaf(a.y, x1.z, ACC[(cc)*4+2]);               \
    ACC[(cc)*4+2] = fmaf(a.z, x2.z, ACC[(cc)*4+2]);               \
    ACC[(cc)*4+2] = fmaf(a.w, x3.z, ACC[(cc)*4+2]);               \
    ACC[(cc)*4+3] = fmaf(a.x, x0.w, ACC[(cc)*4+3]);               \
    ACC[(cc)*4+3] = fmaf(a.y, x1.w, ACC[(cc)*4+3]);               \
    ACC[(cc)*4+3] = fmaf(a.z, x2.w, ACC[(cc)*4+3]);               \
    ACC[(cc)*4+3] = fmaf(a.w, x3.w, ACC[(cc)*4+3]);

#define GEMM_TILE(ACC, SA, row0)                                              \
    _Pragma("unroll")                                                         \
    for (int k0 = 0; k0 < 32; k0 += 4) {                                      \
        const float4 x0 = *(const float4*)&sX[(k0+0)*Tv + t0];                \
        const float4 x1 = *(const float4*)&sX[(k0+1)*Tv + t0];                \
        const float4 x2 = *(const float4*)&sX[(k0+2)*Tv + t0];                \
        const float4 x3 = *(const float4*)&sX[(k0+3)*Tv + t0];                \
        { const float4 a = *(const float4*)&(SA)[((row0)+0)*36 + k0]; GEMM_CC(ACC,0,a) } \
        { const float4 a = *(const float4*)&(SA)[((row0)+1)*36 + k0]; GEMM_CC(ACC,1,a) } \
        { const float4 a = *(const float4*)&(SA)[((row0)+2)*36 + k0]; GEMM_CC(ACC,2,a) } \
        { const float4 a = *(const float4*)&(SA)[((row0)+3)*36 + k0]; GEMM_CC(ACC,3,a) } \
    }

__global__ __launch_bounds__(512, 2)
void kf_fused(const float* __restrict__ inp,
              const float* __restrict__ Qws, const float* __restrict__ Mfull,
              const float* __restrict__ W2f, const float* __restrict__ B2f,
              const float* __restrict__ a2,
              float* __restrict__ out)
{
    __shared__ __align__(16) float sX[DCv * Tv];   // 64 KB [k][t]: Q, then P
    __shared__ __align__(16) float sM[DCv * 36];   // 4.5 KB (pad 36: bank spread)
    __shared__ __align__(16) float sW[Cv * 36];    // 9 KB
    __shared__ float sPart[8][DCv];                // wave partials (mx, then sum)
    __shared__ float sMx[DCv], sRZ[DCv];
    __shared__ float sB2[Cv];

    const int tid = threadIdx.x;
    const int bf  = blockIdx.x;
    const int b   = bf >> 7;
    const int f   = bf & 127;
    const int w   = tid >> 6;
    const int l   = tid & 63;
    const int tl  = l & 15;
    const int cl  = l >> 4;
    const int t0  = w * 64 + tl * 4;          // this lane's 4 t-columns
    const int limit = f + (Tv - Fv + 1);      // valid iff t < limit (385..512)
    const float alpha2 = a2[0];

    // ---- stage: q column (8 x b128 global), M, W2f, B2f ----
    const float* qg = Qws + ((size_t)bf * Tv + tid) * DCv;
    float4 q0 = *(const float4*)&qg[0],  q1 = *(const float4*)&qg[4];
    float4 q2 = *(const float4*)&qg[8],  q3 = *(const float4*)&qg[12];
    float4 q4 = *(const float4*)&qg[16], q5 = *(const float4*)&qg[20];
    float4 q6 = *(const float4*)&qg[24], q7 = *(const float4*)&qg[28];

    if (tid < 256) {
        const int c = tid >> 3, k0 = (tid & 7) << 2;
        float4 v = *(const float4*)&Mfull[(size_t)bf * 1024 + tid * 4];
        *(float4*)&sM[c * 36 + k0] = v;
    }
    {
        const int c = tid >> 3, k0 = (tid & 7) << 2;
        float4 v = *(const float4*)&W2f[tid * 4];
        *(float4*)&sW[c * 36 + k0] = v;
    }
    if (tid < Cv) sB2[tid] = B2f[tid];

    // q -> sX[k][t] (lanes write consecutive t: conflict-free)
    {
        const int t = tid;
        sX[ 0*Tv+t]=q0.x; sX[ 1*Tv+t]=q0.y; sX[ 2*Tv+t]=q0.z; sX[ 3*Tv+t]=q0.w;
        sX[ 4*Tv+t]=q1.x; sX[ 5*Tv+t]=q1.y; sX[ 6*Tv+t]=q1.z; sX[ 7*Tv+t]=q1.w;
        sX[ 8*Tv+t]=q2.x; sX[ 9*Tv+t]=q2.y; sX[10*Tv+t]=q2.z; sX[11*Tv+t]=q2.w;
        sX[12*Tv+t]=q3.x; sX[13*Tv+t]=q3.y; sX[14*Tv+t]=q3.z; sX[15*Tv+t]=q3.w;
        sX[16*Tv+t]=q4.x; sX[17*Tv+t]=q4.y; sX[18*Tv+t]=q4.z; sX[19*Tv+t]=q4.w;
        sX[20*Tv+t]=q5.x; sX[21*Tv+t]=q5.y; sX[22*Tv+t]=q5.z; sX[23*Tv+t]=q5.w;
        sX[24*Tv+t]=q6.x; sX[25*Tv+t]=q6.y; sX[26*Tv+t]=q6.z; sX[27*Tv+t]=q6.w;
        sX[28*Tv+t]=q7.x; sX[29*Tv+t]=q7.y; sX[30*Tv+t]=q7.z; sX[31*Tv+t]=q7.w;
    }
    __syncthreads();

    // ---- GEMM1: O[32c][t-slice] in two 16c tiles; lane holds 4c x 4t each ----
    float oA[16], oB[16];
    #pragma unroll
    for (int i = 0; i < 16; ++i) { oA[i] = 0.f; oB[i] = 0.f; }
    const int cA = cl * 4;          // c-tile A rows
    const int cB = 16 + cl * 4;     // c-tile B rows
    GEMM_TILE(oA, sM, cA)
    GEMM_TILE(oB, sM, cB)

    // ---- mask (columns t >= limit get -inf) ----
    #pragma unroll
    for (int jt = 0; jt < 4; ++jt) {
        if (t0 + jt >= limit) {
            #pragma unroll
            for (int cc = 0; cc < 4; ++cc) { oA[cc*4+jt] = -INFINITY; oB[cc*4+jt] = -INFINITY; }
        }
    }

    // ---- stats pass 1: per-(wave,c) max over the wave's 64 t ----
    #pragma unroll
    for (int cc = 0; cc < 4; ++cc) {
        float mA = fmaxf(fmaxf(oA[cc*4+0], oA[cc*4+1]), fmaxf(oA[cc*4+2], oA[cc*4+3]));
        float mB = fmaxf(fmaxf(oB[cc*4+0], oB[cc*4+1]), fmaxf(oB[cc*4+2], oB[cc*4+3]));
        #pragma unroll
        for (int s = 1; s < 16; s <<= 1) {
            mA = fmaxf(mA, __shfl_xor(mA, s));
            mB = fmaxf(mB, __shfl_xor(mB, s));
        }
        if (tl == 0) { sPart[w][cA + cc] = mA; sPart[w][cB + cc] = mB; }
    }
    __syncthreads();
    if (tid < DCv) {
        float m = sPart[0][tid];
        #pragma unroll
        for (int ww = 1; ww < 8; ++ww) m = fmaxf(m, sPart[ww][tid]);
        sMx[tid] = m;
    }
    __syncthreads();

    // ---- exp + pass 2: per-(wave,c) sum ----
    #pragma unroll
    for (int cc = 0; cc < 4; ++cc) {
        const float mxA = sMx[cA + cc], mxB = sMx[cB + cc];
        float sA = 0.f, sB = 0.f;
        #pragma unroll
        for (int jt = 0; jt < 4; ++jt) {
            oA[cc*4+jt] = __expf(oA[cc*4+jt] - mxA); sA += oA[cc*4+jt];
            oB[cc*4+jt] = __expf(oB[cc*4+jt] - mxB); sB += oB[cc*4+jt];
        }
        #pragma unroll
        for (int s = 1; s < 16; s <<= 1) {
            sA += __shfl_xor(sA, s);
            sB += __shfl_xor(sB, s);
        }
        if (tl == 0) { sPart[w][cA + cc] = sA; sPart[w][cB + cc] = sB; }
    }
    __syncthreads();
    if (tid < DCv) {
        float z = 0.f;
        #pragma unroll
        for (int ww = 0; ww < 8; ++ww) z += sPart[ww][tid];
        sRZ[tid] = 1.f / z;
    }
    __syncthreads();

    // ---- P = e * rz -> overwrite sX[c][t] ----
    #pragma unroll
    for (int cc = 0; cc < 4; ++cc) {
        const float rA = sRZ[cA + cc], rB = sRZ[cB + cc];
        float4 pA, pB;
        pA.x = oA[cc*4+0]*rA; pA.y = oA[cc*4+1]*rA; pA.z = oA[cc*4+2]*rA; pA.w = oA[cc*4+3]*rA;
        pB.x = oB[cc*4+0]*rB; pB.y = oB[cc*4+1]*rB; pB.z = oB[cc*4+2]*rB; pB.w = oB[cc*4+3]*rB;
        *(float4*)&sX[(cA + cc)*Tv + t0] = pA;
        *(float4*)&sX[(cB + cc)*Tv + t0] = pB;
    }
    __syncthreads();

    // ---- GEMM2: OUT[64oc][t-slice] in four 16oc iterations + fused epilogue ----
    #pragma unroll 1
    for (int it = 0; it < 4; ++it) {
        const int oc0 = it * 16 + cl * 4;
        const float* rp = inp + ((size_t)(b * Cv + oc0) * Fv + f) * Tv + t0;
        float4 r0 = *(const float4*)&rp[0];
        float4 r1 = *(const float4*)&rp[(size_t)1 * FT];
        float4 r2 = *(const float4*)&rp[(size_t)2 * FT];
        float4 r3 = *(const float4*)&rp[(size_t)3 * FT];

        float acc[16];
        #pragma unroll
        for (int i = 0; i < 16; ++i) acc[i] = 0.f;
        GEMM_TILE(acc, sW, oc0)

        float* po = out + ((size_t)(b * Cv + oc0) * Fv + f) * Tv + t0;
        #define EPI(cc, RV, ROWOFF) {                                         \
            const float bb = sB2[oc0 + (cc)];                                 \
            float z0 = acc[(cc)*4+0] + bb, z1 = acc[(cc)*4+1] + bb;           \
            float z2 = acc[(cc)*4+2] + bb, z3 = acc[(cc)*4+3] + bb;           \
            z0 = z0 >= 0.f ? z0 : alpha2 * z0;                                \
            z1 = z1 >= 0.f ? z1 : alpha2 * z1;                                \
            z2 = z2 >= 0.f ? z2 : alpha2 * z2;                                \
            z3 = z3 >= 0.f ? z3 : alpha2 * z3;                                \
            float4 o4; o4.x = z0 + RV.x; o4.y = z1 + RV.y;                    \
            o4.z = z2 + RV.z; o4.w = z3 + RV.w;                               \
            *(float4*)&po[(size_t)(ROWOFF) * FT] = o4; }
        EPI(0, r0, 0)
        EPI(1, r1, 1)
        EPI(2, r2, 2)
        EPI(3, r3, 3)
        #undef EPI
    }
}

extern "C" void kernel_launch(void* const* d_in, const int* in_sizes, int n_in,
                              void* d_out, int out_size, void* d_ws, size_t ws_size,
                              hipStream_t stream) {
    const float* inp = (const float*)d_in[0];
    const float* w1  = (const float*)d_in[1];
    const float* b1  = (const float*)d_in[2];
    const float* g1  = (const float*)d_in[3];
    const float* be1 = (const float*)d_in[4];
    const float* m1  = (const float*)d_in[5];
    const float* v1  = (const float*)d_in[6];
    const float* a1  = (const float*)d_in[7];
    const float* wp  = (const float*)d_in[8];
    const float* bp  = (const float*)d_in[9];
    const float* g2  = (const float*)d_in[10];
    const float* be2 = (const float*)d_in[11];
    const float* m2  = (const float*)d_in[12];
    const float* v2  = (const float*)d_in[13];
    const float* a2  = (const float*)d_in[14];

    float* Qws   = (float*)d_ws;                            // 8,388,608 f = 33.6 MB
    float* Mfull = Qws   + (size_t)Bv * Fv * Tv * DCv;      //   524,288 f =  2.1 MB
    float* W2f   = Mfull + (size_t)512 * 1024;              //     2,048 f
    float* B2f   = W2f   + 2048;                            //        64 f

    kprep<<<dim3(1), dim3(512), 0, stream>>>(wp, bp, g2, be2, m2, v2, W2f, B2f);
    k1_conv<<<dim3(Bv * Fv * 2), dim3(256), 0, stream>>>(
        inp, w1, b1, g1, be1, m1, v1, a1, Qws);
    km_build<<<dim3(Bv * Fv), dim3(256), 0, stream>>>(Qws, Mfull);
    kf_fused<<<dim3(Bv * Fv), dim3(512), 0, stream>>>(
        inp, Qws, Mfull, W2f, B2f, a2, (float*)d_out);
}

// Round 12
// 109.878 us; speedup vs baseline: 1.3340x; 1.0143x over previous
//
#include <hip/hip_runtime.h>
#include <math.h>

#define Bv  4
#define Cv  64
#define DCv 32
#define Fv  128
#define Tv  512
#define FT  (Fv * 512)

// ---------------------------------------------------------------------------
// KPREP: fold BN scales into both conv weights.
// W1f[c][k] = w1[c][k] * s1[c]   (32 x 64)   B1f[c]  = (b1-m1)*s1 + be1
// W2f[o][k] = wp[o][k] * s2[o]   (64 x 32)   B2f[o]  = (bp-m2)*s2 + be2
// ---------------------------------------------------------------------------
__global__ __launch_bounds__(512)
void kprep(const float* __restrict__ w1, const float* __restrict__ b1,
           const float* __restrict__ g1, const float* __restrict__ be1,
           const float* __restrict__ m1, const float* __restrict__ v1,
           const float* __restrict__ wp, const float* __restrict__ bp,
           const float* __restrict__ g2, const float* __restrict__ be2,
           const float* __restrict__ m2, const float* __restrict__ v2,
           float* __restrict__ W1f, float* __restrict__ B1f,
           float* __restrict__ W2f, float* __restrict__ B2f)
{
    const int tid = threadIdx.x;   // 512: one float4 of W1f and one of W2f each
    {
        const int c = tid >> 4;                    // 16 float4 per 64-wide row
        const float s = g1[c] * rsqrtf(v1[c] + 1e-5f);
        float4 v = *(const float4*)&w1[tid * 4];
        v.x *= s; v.y *= s; v.z *= s; v.w *= s;
        *(float4*)&W1f[tid * 4] = v;
    }
    {
        const int o = tid >> 3;                    // 8 float4 per 32-wide row
        const float s = g2[o] * rsqrtf(v2[o] + 1e-5f);
        float4 v = *(const float4*)&wp[tid * 4];
        v.x *= s; v.y *= s; v.z *= s; v.w *= s;
        *(float4*)&W2f[tid * 4] = v;
    }
    if (tid < DCv) {
        const float s = g1[tid] * rsqrtf(v1[tid] + 1e-5f);
        B1f[tid] = (b1[tid] - m1[tid]) * s + be1[tid];
    }
    if (tid < Cv) {
        const float s = g2[tid] * rsqrtf(v2[tid] + 1e-5f);
        B2f[tid] = (bp[tid] - m2[tid]) * s + be2[tid];
    }
}

// ---------------------------------------------------------------------------
// KG1: conv1 as a wave-tiled GEMM. One block per bf, 512 thr (8 waves).
// Q[32][512] = prelu(W1f[32][64] * X[64][512] + B1f). Two 256-t slices:
// stage X[64][256] (64 KB, coalesced float4), then wave w computes rows
// w*4..w*4+3 over all 256 t (lane = 4 t). A-operand from SGPR (wave-uniform
// rows), x via ds_read_b128 -> 16 FMA per LDS read. ~50 VGPR by construction.
// ---------------------------------------------------------------------------
__global__ __launch_bounds__(512, 2)
void kg1_conv(const float* __restrict__ inp,
              const float* __restrict__ W1f, const float* __restrict__ B1f,
              const float* __restrict__ a1,
              float* __restrict__ Qws)
{
    __shared__ __align__(16) float sX[Cv * 256];   // 64 KB, row stride 256

    const int tid = threadIdx.x;
    const int bf  = blockIdx.x;
    const int b   = bf >> 7;
    const int f   = bf & 127;
    const int w   = tid >> 6;
    const int l   = tid & 63;
    const int c0  = __builtin_amdgcn_readfirstlane(w) * 4;   // wave-uniform rows
    const float alpha1 = a1[0];

    const float* binp = inp + (size_t)(b * Cv) * FT + f * 512;

    #pragma unroll 1
    for (int s = 0; s < 2; ++s) {
        // ---- stage slice s: 4096 float4, 8 per thread, coalesced ----
        if (s) __syncthreads();               // protect sX reuse
        #pragma unroll
        for (int i = 0; i < 8; ++i) {
            const int idx = tid + i * 512;    // 0..4095
            const int ch  = idx >> 6;
            const int tt  = idx & 63;
            float4 v = *(const float4*)&binp[(size_t)ch * FT + s * 256 + tt * 4];
            *(float4*)&sX[ch * 256 + tt * 4] = v;
        }
        __syncthreads();

        // ---- GEMM: rows c0..c0+3, cols t0..t0+3 ----
        const int t0 = l * 4;
        float acc[16];
        #pragma unroll
        for (int i = 0; i < 16; ++i) acc[i] = 0.f;

        #pragma unroll
        for (int k0 = 0; k0 < Cv; k0 += 4) {
            const float4 x0 = *(const float4*)&sX[(k0+0) * 256 + t0];
            const float4 x1 = *(const float4*)&sX[(k0+1) * 256 + t0];
            const float4 x2 = *(const float4*)&sX[(k0+2) * 256 + t0];
            const float4 x3 = *(const float4*)&sX[(k0+3) * 256 + t0];
            #pragma unroll
            for (int r = 0; r < 4; ++r) {
                const float* wr = W1f + (c0 + r) * Cv + k0;   // uniform -> s_load
                const float m0 = wr[0], m1 = wr[1], m2 = wr[2], m3 = wr[3];
                acc[r*4+0] = fmaf(m0, x0.x, acc[r*4+0]); acc[r*4+0] = fmaf(m1, x1.x, acc[r*4+0]);
                acc[r*4+0] = fmaf(m2, x2.x, acc[r*4+0]); acc[r*4+0] = fmaf(m3, x3.x, acc[r*4+0]);
                acc[r*4+1] = fmaf(m0, x0.y, acc[r*4+1]); acc[r*4+1] = fmaf(m1, x1.y, acc[r*4+1]);
                acc[r*4+1] = fmaf(m2, x2.y, acc[r*4+1]); acc[r*4+1] = fmaf(m3, x3.y, acc[r*4+1]);
                acc[r*4+2] = fmaf(m0, x0.z, acc[r*4+2]); acc[r*4+2] = fmaf(m1, x1.z, acc[r*4+2]);
                acc[r*4+2] = fmaf(m2, x2.z, acc[r*4+2]); acc[r*4+2] = fmaf(m3, x3.z, acc[r*4+2]);
                acc[r*4+3] = fmaf(m0, x0.w, acc[r*4+3]); acc[r*4+3] = fmaf(m1, x1.w, acc[r*4+3]);
                acc[r*4+3] = fmaf(m2, x2.w, acc[r*4+3]); acc[r*4+3] = fmaf(m3, x3.w, acc[r*4+3]);
            }
        }

        // ---- epilogue: +bias, PReLU, store Q[t][c0..c0+3] ----
        const float b0 = B1f[c0+0], b1_ = B1f[c0+1], b2 = B1f[c0+2], b3 = B1f[c0+3];
        #pragma unroll
        for (int jt = 0; jt < 4; ++jt) {
            const int t = s * 256 + t0 + jt;
            float z0 = acc[0*4+jt] + b0, z1 = acc[1*4+jt] + b1_;
            float z2 = acc[2*4+jt] + b2, z3 = acc[3*4+jt] + b3;
            float4 v;
            v.x = z0 >= 0.f ? z0 : alpha1 * z0;
            v.y = z1 >= 0.f ? z1 : alpha1 * z1;
            v.z = z2 >= 0.f ? z2 : alpha1 * z2;
            v.w = z3 >= 0.f ? z3 : alpha1 * z3;
            *(float4*)&Qws[((size_t)bf * Tv + t) * DCv + c0] = v;
        }
    }
}

// ---------------------------------------------------------------------------
// KM: M = Q Q^T / sqrt(32). One block per bf. Proven pattern (~5 us total).
// ---------------------------------------------------------------------------
__global__ __launch_bounds__(256)
void km_build(const float* __restrict__ Qws, float* __restrict__ Mfull)
{
    __shared__ __align__(16) float sP[4][1024];  // 16 KB

    const int tid   = threadIdx.x;
    const int bf    = blockIdx.x;
    const int slice = tid >> 6;
    const int l     = tid & 63;
    const int c1b   = l >> 3;
    const int c2b   = l & 7;

    const float* qp = Qws + ((size_t)bf * Tv + slice * 128) * DCv;
    float4 r0 = {0,0,0,0}, r1 = {0,0,0,0}, r2 = {0,0,0,0}, r3 = {0,0,0,0};
    #pragma unroll 4
    for (int i = 0; i < 128; ++i) {
        const float4 qa = *(const float4*)&qp[i * 32 + c1b * 4];
        const float4 qb = *(const float4*)&qp[i * 32 + c2b * 4];
        r0.x = fmaf(qa.x, qb.x, r0.x); r0.y = fmaf(qa.x, qb.y, r0.y);
        r0.z = fmaf(qa.x, qb.z, r0.z); r0.w = fmaf(qa.x, qb.w, r0.w);
        r1.x = fmaf(qa.y, qb.x, r1.x); r1.y = fmaf(qa.y, qb.y, r1.y);
        r1.z = fmaf(qa.y, qb.z, r1.z); r1.w = fmaf(qa.y, qb.w, r1.w);
        r2.x = fmaf(qa.z, qb.x, r2.x); r2.y = fmaf(qa.z, qb.y, r2.y);
        r2.z = fmaf(qa.z, qb.z, r2.z); r2.w = fmaf(qa.z, qb.w, r2.w);
        r3.x = fmaf(qa.w, qb.x, r3.x); r3.y = fmaf(qa.w, qb.y, r3.y);
        r3.z = fmaf(qa.w, qb.z, r3.z); r3.w = fmaf(qa.w, qb.w, r3.w);
    }
    *(float4*)&sP[slice][(c1b * 4 + 0) * DCv + c2b * 4] = r0;
    *(float4*)&sP[slice][(c1b * 4 + 1) * DCv + c2b * 4] = r1;
    *(float4*)&sP[slice][(c1b * 4 + 2) * DCv + c2b * 4] = r2;
    *(float4*)&sP[slice][(c1b * 4 + 3) * DCv + c2b * 4] = r3;
    __syncthreads();

    const float INV = 0.17677669529663687f;  // 1/sqrt(32)
    float4 v0 = *(const float4*)&sP[0][tid * 4];
    float4 v1 = *(const float4*)&sP[1][tid * 4];
    float4 v2 = *(const float4*)&sP[2][tid * 4];
    float4 v3 = *(const float4*)&sP[3][tid * 4];
    float4 o;
    o.x = ((v0.x + v1.x) + (v2.x + v3.x)) * INV;
    o.y = ((v0.y + v1.y) + (v2.y + v3.y)) * INV;
    o.z = ((v0.z + v1.z) + (v2.z + v3.z)) * INV;
    o.w = ((v0.w + v1.w) + (v2.w + v3.w)) * INV;
    *(float4*)&Mfull[(size_t)bf * 1024 + tid * 4] = o;
}

// ---------------------------------------------------------------------------
// KF: fused O = M*Q -> mask -> softmax -> P -> OUT = W2f*P + B2f -> PReLU ->
// +residual. One block per bf, 512 thr. Wave w: th=w&1 (t-half), grp=w>>1.
// GEMM1: rows grp*8..+7 (8-row tile, M from SGPR); GEMM2: rows grp*16..+15
// in 2 passes (W2f from SGPR). x via ds_read_b128: 32 b128/GEMM1, 64/GEMM2
// per thread (was 384 total in r11 -> LDS-pipe bound at 31 us).
// ---------------------------------------------------------------------------
__global__ __launch_bounds__(512, 2)
void kf_fused(const float* __restrict__ inp,
              const float* __restrict__ Qws, const float* __restrict__ Mfull,
              const float* __restrict__ W2f, const float* __restrict__ B2f,
              const float* __restrict__ a2,
              float* __restrict__ out)
{
    __shared__ __align__(16) float sX[DCv * Tv];   // 64 KB [k][t]: Q, then P
    __shared__ float sPart[8][8];
    __shared__ float sMx[DCv], sRZ[DCv];

    const int tid = threadIdx.x;
    const int bf  = blockIdx.x;
    const int b   = bf >> 7;
    const int f   = bf & 127;
    const int w   = tid >> 6;
    const int l   = tid & 63;
    const int th  = __builtin_amdgcn_readfirstlane(w & 1);
    const int grp = __builtin_amdgcn_readfirstlane(w >> 1);
    const int t0  = th * 256 + l * 4;
    const int limit = f + (Tv - Fv + 1);      // valid iff t < limit (385..512)
    const float alpha2 = a2[0];

    // ---- stage Q columns -> sX[k][t] ----
    {
        const float* qg = Qws + ((size_t)bf * Tv + tid) * DCv;
        float4 q0 = *(const float4*)&qg[0],  q1 = *(const float4*)&qg[4];
        float4 q2 = *(const float4*)&qg[8],  q3 = *(const float4*)&qg[12];
        float4 q4 = *(const float4*)&qg[16], q5 = *(const float4*)&qg[20];
        float4 q6 = *(const float4*)&qg[24], q7 = *(const float4*)&qg[28];
        const int t = tid;
        sX[ 0*Tv+t]=q0.x; sX[ 1*Tv+t]=q0.y; sX[ 2*Tv+t]=q0.z; sX[ 3*Tv+t]=q0.w;
        sX[ 4*Tv+t]=q1.x; sX[ 5*Tv+t]=q1.y; sX[ 6*Tv+t]=q1.z; sX[ 7*Tv+t]=q1.w;
        sX[ 8*Tv+t]=q2.x; sX[ 9*Tv+t]=q2.y; sX[10*Tv+t]=q2.z; sX[11*Tv+t]=q2.w;
        sX[12*Tv+t]=q3.x; sX[13*Tv+t]=q3.y; sX[14*Tv+t]=q3.z; sX[15*Tv+t]=q3.w;
        sX[16*Tv+t]=q4.x; sX[17*Tv+t]=q4.y; sX[18*Tv+t]=q4.z; sX[19*Tv+t]=q4.w;
        sX[20*Tv+t]=q5.x; sX[21*Tv+t]=q5.y; sX[22*Tv+t]=q5.z; sX[23*Tv+t]=q5.w;
        sX[24*Tv+t]=q6.x; sX[25*Tv+t]=q6.y; sX[26*Tv+t]=q6.z; sX[27*Tv+t]=q6.w;
        sX[28*Tv+t]=q7.x; sX[29*Tv+t]=q7.y; sX[30*Tv+t]=q7.z; sX[31*Tv+t]=q7.w;
    }
    __syncthreads();

    // ---- GEMM1: acc[8r x 4t], M rows grp*8..+7 from SGPR ----
    float acc[32];
    #pragma unroll
    for (int i = 0; i < 32; ++i) acc[i] = 0.f;
    {
        const float* Mg = Mfull + (size_t)bf * 1024 + grp * 8 * DCv;
        #pragma unroll
        for (int k0 = 0; k0 < DCv; k0 += 4) {
            const float4 x0 = *(const float4*)&sX[(k0+0)*Tv + t0];
            const float4 x1 = *(const float4*)&sX[(k0+1)*Tv + t0];
            const float4 x2 = *(const float4*)&sX[(k0+2)*Tv + t0];
            const float4 x3 = *(const float4*)&sX[(k0+3)*Tv + t0];
            #pragma unroll
            for (int r = 0; r < 8; ++r) {
                const float* mr = Mg + r * DCv + k0;
                const float m0 = mr[0], m1 = mr[1], m2 = mr[2], m3 = mr[3];
                acc[r*4+0] = fmaf(m0, x0.x, acc[r*4+0]); acc[r*4+0] = fmaf(m1, x1.x, acc[r*4+0]);
                acc[r*4+0] = fmaf(m2, x2.x, acc[r*4+0]); acc[r*4+0] = fmaf(m3, x3.x, acc[r*4+0]);
                acc[r*4+1] = fmaf(m0, x0.y, acc[r*4+1]); acc[r*4+1] = fmaf(m1, x1.y, acc[r*4+1]);
                acc[r*4+1] = fmaf(m2, x2.y, acc[r*4+1]); acc[r*4+1] = fmaf(m3, x3.y, acc[r*4+1]);
                acc[r*4+2] = fmaf(m0, x0.z, acc[r*4+2]); acc[r*4+2] = fmaf(m1, x1.z, acc[r*4+2]);
                acc[r*4+2] = fmaf(m2, x2.z, acc[r*4+2]); acc[r*4+2] = fmaf(m3, x3.z, acc[r*4+2]);
                acc[r*4+3] = fmaf(m0, x0.w, acc[r*4+3]); acc[r*4+3] = fmaf(m1, x1.w, acc[r*4+3]);
                acc[r*4+3] = fmaf(m2, x2.w, acc[r*4+3]); acc[r*4+3] = fmaf(m3, x3.w, acc[r*4+3]);
            }
        }
    }

    // ---- mask ----
    #pragma unroll
    for (int jt = 0; jt < 4; ++jt) {
        if (t0 + jt >= limit) {
            #pragma unroll
            for (int r = 0; r < 8; ++r) acc[r*4+jt] = -INFINITY;
        }
    }

    // ---- row max (wave butterfly + 2-wave combine) ----
    #pragma unroll
    for (int r = 0; r < 8; ++r) {
        float m = fmaxf(fmaxf(acc[r*4+0], acc[r*4+1]), fmaxf(acc[r*4+2], acc[r*4+3]));
        #pragma unroll
        for (int s = 1; s < 64; s <<= 1) m = fmaxf(m, __shfl_xor(m, s));
        if (l == 0) sPart[w][r] = m;
    }
    __syncthreads();
    if (tid < DCv) {
        const int g = tid >> 3, r = tid & 7;
        sMx[tid] = fmaxf(sPart[2*g][r], sPart[2*g+1][r]);
    }
    __syncthreads();

    // ---- exp + row sum ----
    #pragma unroll
    for (int r = 0; r < 8; ++r) {
        const float mx = sMx[grp * 8 + r];
        float sum = 0.f;
        #pragma unroll
        for (int jt = 0; jt < 4; ++jt) {
            acc[r*4+jt] = __expf(acc[r*4+jt] - mx);
            sum += acc[r*4+jt];
        }
        #pragma unroll
        for (int s = 1; s < 64; s <<= 1) sum += __shfl_xor(sum, s);
        if (l == 0) sPart[w][r] = sum;
    }
    __syncthreads();
    if (tid < DCv) {
        const int g = tid >> 3, r = tid & 7;
        sRZ[tid] = 1.f / (sPart[2*g][r] + sPart[2*g+1][r]);
    }
    __syncthreads();

    // ---- P -> sX rows grp*8..+7 ----
    #pragma unroll
    for (int r = 0; r < 8; ++r) {
        const float rz = sRZ[grp * 8 + r];
        float4 p;
        p.x = acc[r*4+0] * rz; p.y = acc[r*4+1] * rz;
        p.z = acc[r*4+2] * rz; p.w = acc[r*4+3] * rz;
        *(float4*)&sX[(grp * 8 + r) * Tv + t0] = p;
    }
    __syncthreads();

    // ---- GEMM2: oc rows grp*16..+15 in 2 passes of 8 ----
    #pragma unroll 1
    for (int p = 0; p < 2; ++p) {
        const int oc0 = grp * 16 + p * 8;
        const float* rp = inp + (size_t)(b * Cv + oc0) * FT + f * 512 + t0;

        float4 rin[8];
        #pragma unroll
        for (int r = 0; r < 8; ++r) rin[r] = *(const float4*)&rp[(size_t)r * FT];

        float acc2[32];
        #pragma unroll
        for (int i = 0; i < 32; ++i) acc2[i] = 0.f;
        const float* Wg = W2f + oc0 * DCv;
        #pragma unroll
        for (int k0 = 0; k0 < DCv; k0 += 4) {
            const float4 x0 = *(const float4*)&sX[(k0+0)*Tv + t0];
            const float4 x1 = *(const float4*)&sX[(k0+1)*Tv + t0];
            const float4 x2 = *(const float4*)&sX[(k0+2)*Tv + t0];
            const float4 x3 = *(const float4*)&sX[(k0+3)*Tv + t0];
            #pragma unroll
            for (int r = 0; r < 8; ++r) {
                const float* wr = Wg + r * DCv + k0;
                const float m0 = wr[0], m1 = wr[1], m2 = wr[2], m3 = wr[3];
                acc2[r*4+0] = fmaf(m0, x0.x, acc2[r*4+0]); acc2[r*4+0] = fmaf(m1, x1.x, acc2[r*4+0]);
                acc2[r*4+0] = fmaf(m2, x2.x, acc2[r*4+0]); acc2[r*4+0] = fmaf(m3, x3.x, acc2[r*4+0]);
                acc2[r*4+1] = fmaf(m0, x0.y, acc2[r*4+1]); acc2[r*4+1] = fmaf(m1, x1.y, acc2[r*4+1]);
                acc2[r*4+1] = fmaf(m2, x2.y, acc2[r*4+1]); acc2[r*4+1] = fmaf(m3, x3.y, acc2[r*4+1]);
                acc2[r*4+2] = fmaf(m0, x0.z, acc2[r*4+2]); acc2[r*4+2] = fmaf(m1, x1.z, acc2[r*4+2]);
                acc2[r*4+2] = fmaf(m2, x2.z, acc2[r*4+2]); acc2[r*4+2] = fmaf(m3, x3.z, acc2[r*4+2]);
                acc2[r*4+3] = fmaf(m0, x0.w, acc2[r*4+3]); acc2[r*4+3] = fmaf(m1, x1.w, acc2[r*4+3]);
                acc2[r*4+3] = fmaf(m2, x2.w, acc2[r*4+3]); acc2[r*4+3] = fmaf(m3, x3.w, acc2[r*4+3]);
            }
        }

        float* po = out + (size_t)(b * Cv + oc0) * FT + f * 512 + t0;
        #pragma unroll
        for (int r = 0; r < 8; ++r) {
            const float bb = B2f[oc0 + r];    // uniform -> s_load
            float z0 = acc2[r*4+0] + bb, z1 = acc2[r*4+1] + bb;
            float z2 = acc2[r*4+2] + bb, z3 = acc2[r*4+3] + bb;
            z0 = z0 >= 0.f ? z0 : alpha2 * z0;
            z1 = z1 >= 0.f ? z1 : alpha2 * z1;
            z2 = z2 >= 0.f ? z2 : alpha2 * z2;
            z3 = z3 >= 0.f ? z3 : alpha2 * z3;
            float4 o4;
            o4.x = z0 + rin[r].x; o4.y = z1 + rin[r].y;
            o4.z = z2 + rin[r].z; o4.w = z3 + rin[r].w;
            *(float4*)&po[(size_t)r * FT] = o4;
        }
    }
}

extern "C" void kernel_launch(void* const* d_in, const int* in_sizes, int n_in,
                              void* d_out, int out_size, void* d_ws, size_t ws_size,
                              hipStream_t stream) {
    const float* inp = (const float*)d_in[0];
    const float* w1  = (const float*)d_in[1];
    const float* b1  = (const float*)d_in[2];
    const float* g1  = (const float*)d_in[3];
    const float* be1 = (const float*)d_in[4];
    const float* m1  = (const float*)d_in[5];
    const float* v1  = (const float*)d_in[6];
    const float* a1  = (const float*)d_in[7];
    const float* wp  = (const float*)d_in[8];
    const float* bp  = (const float*)d_in[9];
    const float* g2  = (const float*)d_in[10];
    const float* be2 = (const float*)d_in[11];
    const float* m2  = (const float*)d_in[12];
    const float* v2  = (const float*)d_in[13];
    const float* a2  = (const float*)d_in[14];

    float* Qws   = (float*)d_ws;                            // 8,388,608 f = 33.6 MB
    float* Mfull = Qws   + (size_t)Bv * Fv * Tv * DCv;      //   524,288 f =  2.1 MB
    float* W1f   = Mfull + (size_t)512 * 1024;              //     2,048 f
    float* B1f   = W1f   + 2048;                            //        32 f
    float* W2f   = B1f   + 32;                              //     2,048 f
    float* B2f   = W2f   + 2048;                            //        64 f

    kprep<<<dim3(1), dim3(512), 0, stream>>>(
        w1, b1, g1, be1, m1, v1, wp, bp, g2, be2, m2, v2, W1f, B1f, W2f, B2f);
    kg1_conv<<<dim3(Bv * Fv), dim3(512), 0, stream>>>(inp, W1f, B1f, a1, Qws);
    km_build<<<dim3(Bv * Fv), dim3(256), 0, stream>>>(Qws, Mfull);
    kf_fused<<<dim3(Bv * Fv), dim3(512), 0, stream>>>(
        inp, Qws, Mfull, W2f, B2f, a2, (float*)d_out);
}